// Round 5
// baseline (15.742 us; speedup 1.0000x reference)
//
#include <hip/hip_runtime.h>

#define NFFT    512
#define NBINS   257
#define HOP     256
#define NFRAMES 511
#define TSAMP   131072

// +4 floats of pad per 32-float row: keeps 16B alignment and quad contiguity
// for i%4==0, spreads strided lane patterns across banks.
__device__ __forceinline__ int SWZ(int i) { return i + ((i >> 5) << 2); }

// ============ K1: per-frame FIR kernel generation -> d_ws ============
// 1022 blocks x 128 threads. Fold bins m/256-m into parity coeffs, then
// 65-step Chebyshev pair recurrence; K symmetry gives 4 taps per thread.
// Taps written straight to ws (coalesced symmetric stores), no LDS k-buffer.
__global__ __launch_bounds__(128)
void genker(const float* __restrict__ log_mag, float* __restrict__ wsK)
{
    __shared__ float s_d[2][132];     // [parity][m]; [*][0]=[*][129..131]=0
    __shared__ float s_c[2];          // mag[0], mag[256]

    const int tid = threadIdx.x;
    const int bf  = blockIdx.x;               // 0..1021
    const int b   = bf / NFRAMES;
    const int f   = bf - b * NFRAMES;
    const float* lm = log_mag + ((size_t)b * 512 + f) * NBINS;

    // ---- fold: jobs 0..133 over 128 threads ----
    {
        const int s2 = tid;
        if (s2 == 0) { s_d[0][0] = 0.f; s_d[1][0] = 0.f; }
        else {
            const float a  = __expf(lm[s2]);
            const float c0 = __expf(lm[256 - s2]);
            const float sg = (s2 & 1) ? -1.f : 1.f;
            s_d[0][s2] = sg * (a + c0);
            s_d[1][s2] = sg * (a - c0);
        }
        if (tid < 6) {
            const int s3 = 128 + tid;
            if (s3 == 128) { const float v = __expf(lm[128]); s_d[0][128] = v; s_d[1][128] = v; }
            else if (s3 < 132) { s_d[0][s3] = 0.f; s_d[1][s3] = 0.f; }
            else if (s3 == 132) s_c[0] = __expf(lm[0]);
            else                s_c[1] = __expf(lm[256]);
        }
    }
    __syncthreads();

    // ---- gen: n = tid (0..127); K[n], K[256-n], K[256+n], K[512-n] ----
    float* wk = wsK + (size_t)bf * NFFT;
    {
        const int n    = tid;
        const float t  = __cosf(3.14159265358979323846f * (float)n * (1.0f / 256.0f));
        const float k2 = 2.0f * t;
        const float* dsel = s_d[n & 1];
        float ce = 1.0f, co = t, E = 0.0f, O = 0.0f;
        #pragma unroll 3
        for (int m = 0; m < 132; m += 4) {
            float4 dd = *(const float4*)&dsel[m];
            E = fmaf(dd.x, ce, E);
            O = fmaf(dd.y, co, O);
            float ce2 = fmaf(k2, co,  -ce);
            float co2 = fmaf(k2, ce2, -co);
            E = fmaf(dd.z, ce2, E);
            O = fmaf(dd.w, co2, O);
            ce = fmaf(k2, co2, -ce2);
            co = fmaf(k2, ce,  -co2);
        }
        const float p    = (n & 1) ? -1.f : 1.f;
        const float cst  = s_c[0] + p * s_c[1];
        const float v_lo = (cst + 2.f * (E + O)) * (0.5f * (1.f - t)) * (1.f / 512.f);
        const float v_hi = (cst + 2.f * (E - O)) * (0.5f * (1.f + t)) * (1.f / 512.f);
        wk[n]       = v_lo;
        wk[256 - n] = v_hi;
        if (n > 0) { wk[256 + n] = v_hi; wk[512 - n] = v_lo; }
    }
    // ---- n = 128 degenerate case (cos(m*pi/2)): tid 127 handles it ----
    if (tid == 127) {
        float E = 0.0f;
        #pragma unroll 3
        for (int m = 0; m < 132; m += 4) E += s_d[0][m] - s_d[0][m + 2];
        const float v = (s_c[0] + s_c[1] + 2.f * E) * 0.5f * (1.f / 512.f);
        wk[128] = v; wk[384] = v;
    }
}

// ============ K2: convolution, half-frame per block ============
// 2044 blocks x 128 threads (8 blocks/CU). Stage ex window (640 w) + K
// (512 w from ws/L3) -> one barrier -> NT=16/KT=32 conv -> combine.
__global__ __launch_bounds__(128)
void conv(const float* __restrict__ ex, const float* __restrict__ wsK,
          float* __restrict__ out)
{
    __shared__ float s_ex[720];        // SWZ(639)=715
    __shared__ float s_K[576];         // SWZ(508)=568
    __shared__ float s_part[16][132];

    const int tid = threadIdx.x;
    const int hb  = blockIdx.x;                // 0..2043
    const int bf  = hb >> 1;
    const int b   = bf / NFRAMES;
    const int f   = bf - b * NFRAMES;
    const int j0  = (hb & 1) << 7;             // 0 or 128

    const float* exb = ex + (size_t)b * TSAMP;
    const float* wk  = wsK + (size_t)bf * NFFT;

    // ---- stage ex: w[i] = ex_pad[f*256 + j0 - 255 + i], i = 0..638 ----
    // gbase aligned to 128; quad t covers w[4t-1 .. 4t+2].
    const int gbase = f * HOP + j0 - 256;
    #pragma unroll
    for (int t = tid; t < 160; t += 128) {
        const int gw = gbase + 4 * t;
        float4 q = make_float4(0.f, 0.f, 0.f, 0.f);
        if (gw >= 0) q = *(const float4*)&exb[gw];   // right edge never OOB
        if (t > 0) s_ex[SWZ(4 * t - 1)] = q.x;
        s_ex[SWZ(4 * t)]     = q.y;
        s_ex[SWZ(4 * t + 1)] = q.z;
        s_ex[SWZ(4 * t + 2)] = q.w;
    }
    // ---- stage K (aligned quads, SWZ keeps 16B alignment) ----
    {
        float4 kq = *(const float4*)&wk[4 * tid];
        *(float4*)&s_K[SWZ(4 * tid)] = kq;
    }
    __syncthreads();

    // ---- conv partials: ot = tid&7 (8 tiles x 16 outputs), kt = tid>>3
    //      (16 k-tiles x 32 taps); thread: 16 out x 32 taps = 512 FMA ----
    {
        const int ot  = tid & 7;
        const int kt  = tid >> 3;
        const int kb  = kt * 32;
        const int off = ot * 16 + kb;          // w-window base (mult of 16)
        float w[20];
        #pragma unroll
        for (int c = 0; c < 5; ++c)
            *(float4*)&w[4 * c] = *(const float4*)&s_ex[SWZ(off + 4 * c)];
        float acc[16];
        #pragma unroll
        for (int r = 0; r < 16; ++r) acc[r] = 0.0f;
        #pragma unroll
        for (int kc = 0; kc < 32; kc += 4) {
            const float4 kq = *(const float4*)&s_K[SWZ(kb + kc)];
            #pragma unroll
            for (int r = 0; r < 16; ++r)
                acc[r] = fmaf(w[r], kq.x, fmaf(w[r + 1], kq.y,
                         fmaf(w[r + 2], kq.z, fmaf(w[r + 3], kq.w, acc[r]))));
            if (kc < 28) {
                #pragma unroll
                for (int i = 0; i < 16; ++i) w[i] = w[i + 4];
                *(float4*)&w[16] = *(const float4*)&s_ex[SWZ(off + kc + 20)];
            }
        }
        #pragma unroll
        for (int c = 0; c < 4; ++c)
            *(float4*)&s_part[kt][ot * 16 + 4 * c] =
                make_float4(acc[4 * c], acc[4 * c + 1], acc[4 * c + 2], acc[4 * c + 3]);
    }
    __syncthreads();

    // ---- combine + store ----
    float r = 0.0f;
    #pragma unroll
    for (int p = 0; p < 16; ++p) r += s_part[p][tid];
    out[((size_t)b * NFRAMES + f) * HOP + j0 + tid] = r;
}

extern "C" void kernel_launch(void* const* d_in, const int* in_sizes, int n_in,
                              void* d_out, int out_size, void* d_ws, size_t ws_size,
                              hipStream_t stream)
{
    const float* ex      = (const float*)d_in[0];
    const float* log_mag = (const float*)d_in[1];
    float* outp = (float*)d_out;
    float* wsK  = (float*)d_ws;         // 1022 * 512 floats = 2 MB

    hipLaunchKernelGGL(genker, dim3(2 * NFRAMES), dim3(128), 0, stream, log_mag, wsK);
    hipLaunchKernelGGL(conv,   dim3(4 * NFRAMES), dim3(128), 0, stream, ex, wsK, outp);
}

// Round 6
// 13.598 us; speedup vs baseline: 1.1577x; 1.1577x over previous
//
#include <hip/hip_runtime.h>

#define NFFT    512
#define NBINS   257
#define HOP     256
#define NFRAMES 511
#define TSAMP   131072

// +4 floats of pad per 32-float row: keeps 16B alignment and quad contiguity
// for i%4==0, spreads strided lane patterns across banks.
__device__ __forceinline__ int SWZ(int i) { return i + ((i >> 5) << 2); }

// 511 blocks x 256 threads; each block = TWO frames (half = tid>>7).
// Per frame (128 threads, ht = tid&127):
//  P1: stage ex window (aligned float4 global loads, swizzled LDS stores)
//      + fold bins m/256-m into parity coeff arrays (reads log_mag direct).
//  P2: gen, parity-per-wave (ht<64: even n, else odd); 65-step Chebyshev
//      (E,O) -> 4 taps via K symmetry; ht=127 also does n=128 closed form.
//  P3: conv, 8 output-tiles(32) x 16 k-tiles(32): 32 outs x 32 taps =
//      1024 FMA/thread, 16 ex-b128 + 8 K-b128 per thread.
//  P4: combine 16 partials for 2 outputs/thread, store.
__global__ __launch_bounds__(256)
void ltv_fir2(const float* __restrict__ ex,
              const float* __restrict__ log_mag,
              float* __restrict__ out)
{
    __shared__ float s_d[2][2][132];     // [half][parity][m]
    __shared__ float s_c[2][2];          // [half][{mag0, mag256}]
    __shared__ float s_ker[2][512];
    __shared__ float s_ex[2][872];       // SWZ(770)=866
    __shared__ float s_part[2][16][276]; // 276%32=20 -> kt rows spread banks

    const int tid  = threadIdx.x;
    const int half = tid >> 7;
    const int ht   = tid & 127;
    const int bf   = blockIdx.x * 2 + half;     // 0..1021
    const int b    = bf / NFRAMES;
    const int f    = bf - b * NFRAMES;

    const float* lm  = log_mag + ((size_t)b * 512 + f) * NBINS;
    const float* exb = ex + (size_t)b * TSAMP;

    // ---- P1a: stage ex window: w[i] = ex_pad[f*256 - 255 + i] ----
    // quad t covers i = 4t-1 .. 4t+2 (gbase aligned to 256).
    {
        const int gbase = f * HOP - 256;
        #pragma unroll
        for (int it = 0; it < 2; ++it) {
            const int t = ht + 128 * it;
            if (t < 193) {
                const int gw = gbase + 4 * t;
                float4 q = make_float4(0.f, 0.f, 0.f, 0.f);
                if (gw >= 0 && gw + 3 < TSAMP) q = *(const float4*)&exb[gw];
                if (t > 0) s_ex[half][SWZ(4 * t - 1)] = q.x;
                s_ex[half][SWZ(4 * t)]     = q.y;
                s_ex[half][SWZ(4 * t + 1)] = q.z;
                s_ex[half][SWZ(4 * t + 2)] = q.w;
            }
        }
    }
    // ---- P1b: fold coefficients (jobs 0..133 on 128 threads) ----
    {
        if (ht == 0) { s_d[half][0][0] = 0.f; s_d[half][1][0] = 0.f; }
        else {
            const float a  = __expf(lm[ht]);
            const float c0 = __expf(lm[256 - ht]);
            const float sg = (ht & 1) ? -1.f : 1.f;
            s_d[half][0][ht] = sg * (a + c0);
            s_d[half][1][ht] = sg * (a - c0);
        }
        if (ht < 6) {
            const int s3 = 128 + ht;
            if (s3 == 128) { const float v = __expf(lm[128]); s_d[half][0][128] = v; s_d[half][1][128] = v; }
            else if (s3 < 132) { s_d[half][0][s3] = 0.f; s_d[half][1][s3] = 0.f; }
            else if (s3 == 132) s_c[half][0] = __expf(lm[0]);
            else                s_c[half][1] = __expf(lm[256]);
        }
    }
    __syncthreads();

    // ---- P2: FIR kernel gen ----
    {
        const int n    = 2 * (ht & 63) + (ht >> 6);        // parity uniform/wave
        const float t  = __cosf(3.14159265358979323846f * (float)n * (1.0f / 256.0f));
        const float k2 = 2.0f * t;
        const float* dsel = s_d[half][n & 1];              // wave-uniform ptr
        float ce = 1.0f, co = t, E = 0.0f, O = 0.0f;
        #pragma unroll 3
        for (int m = 0; m < 132; m += 4) {
            float4 dd = *(const float4*)&dsel[m];          // uniform b128 bcast
            E = fmaf(dd.x, ce, E);
            O = fmaf(dd.y, co, O);
            float ce2 = fmaf(k2, co,  -ce);
            float co2 = fmaf(k2, ce2, -co);
            E = fmaf(dd.z, ce2, E);
            O = fmaf(dd.w, co2, O);
            ce = fmaf(k2, co2, -ce2);
            co = fmaf(k2, ce,  -co2);
        }
        const float p    = (n & 1) ? -1.f : 1.f;
        const float cst  = s_c[half][0] + p * s_c[half][1];
        const float v_lo = (cst + 2.f * (E + O)) * (0.5f * (1.f - t)) * (1.f / 512.f);
        const float v_hi = (cst + 2.f * (E - O)) * (0.5f * (1.f + t)) * (1.f / 512.f);
        s_ker[half][n]       = v_lo;
        s_ker[half][256 - n] = v_hi;
        if (n > 0) { s_ker[half][256 + n] = v_hi; s_ker[half][512 - n] = v_lo; }
        if (ht == 127) {                                   // n = 128 closed form
            float E2 = 0.0f;
            #pragma unroll 3
            for (int m = 0; m < 132; m += 4) E2 += s_d[half][0][m] - s_d[half][0][m + 2];
            const float v = (s_c[half][0] + s_c[half][1] + 2.f * E2) * 0.5f * (1.f / 512.f);
            s_ker[half][128] = v; s_ker[half][384] = v;
        }
    }
    __syncthreads();

    // ---- P3: conv partials; thread (ot = ht&7, kt = ht>>3):
    //      outputs j = ot*32 + r (r=0..31), taps k = kt*32 + kc + c ----
    {
        const int ot  = ht & 7;
        const int kt  = ht >> 3;
        const int kb  = kt * 32;
        const int off = ot * 32 + kb;            // ex window base (mult of 32)
        float w[36];
        #pragma unroll
        for (int c = 0; c < 9; ++c)
            *(float4*)&w[4 * c] = *(const float4*)&s_ex[half][SWZ(off + 4 * c)];
        float acc[32];
        #pragma unroll
        for (int r = 0; r < 32; ++r) acc[r] = 0.0f;
        #pragma unroll
        for (int kc = 0; kc < 32; kc += 4) {
            const float4 kq = *(const float4*)&s_ker[half][kb + kc];
            #pragma unroll
            for (int r = 0; r < 32; ++r)
                acc[r] = fmaf(w[r], kq.x, fmaf(w[r + 1], kq.y,
                         fmaf(w[r + 2], kq.z, fmaf(w[r + 3], kq.w, acc[r]))));
            if (kc < 28) {
                #pragma unroll
                for (int i = 0; i < 32; ++i) w[i] = w[i + 4];
                *(float4*)&w[32] = *(const float4*)&s_ex[half][SWZ(off + kc + 36)];
            }
        }
        #pragma unroll
        for (int c = 0; c < 8; ++c)
            *(float4*)&s_part[half][kt][ot * 32 + 4 * c] =
                make_float4(acc[4 * c], acc[4 * c + 1], acc[4 * c + 2], acc[4 * c + 3]);
    }
    __syncthreads();

    // ---- P4: combine + store (2 outputs/thread) ----
    {
        float r0 = 0.0f, r1 = 0.0f;
        #pragma unroll
        for (int p = 0; p < 16; ++p) {
            r0 += s_part[half][p][ht];
            r1 += s_part[half][p][ht + 128];
        }
        float* ob = out + ((size_t)b * NFRAMES + f) * HOP;
        ob[ht]       = r0;
        ob[ht + 128] = r1;
    }
}

extern "C" void kernel_launch(void* const* d_in, const int* in_sizes, int n_in,
                              void* d_out, int out_size, void* d_ws, size_t ws_size,
                              hipStream_t stream)
{
    const float* ex      = (const float*)d_in[0];
    const float* log_mag = (const float*)d_in[1];
    float* outp = (float*)d_out;

    dim3 grid(NFRAMES);      // 511 blocks, 2 frames each = 1022 frames
    dim3 block(256);
    hipLaunchKernelGGL(ltv_fir2, grid, block, 0, stream, ex, log_mag, outp);
}

// Round 7
// 12.781 us; speedup vs baseline: 1.2317x; 1.0639x over previous
//
#include <hip/hip_runtime.h>

#define NFFT    512
#define NBINS   257
#define HOP     256
#define NFRAMES 511
#define TSAMP   131072

// +4 floats of pad per 32-float row: keeps 16B alignment and quad contiguity
// for i%4==0, spreads strided lane patterns to the balanced-bank minimum.
__device__ __forceinline__ int SWZ(int i) { return i + ((i >> 5) << 2); }

// One block per (batch, frame). 256 threads = 4 waves, 3 barriers.
// Phase 1 (parallel): tid<192 stage ex window (aligned float4 global loads,
//   scalar swizzled LDS stores absorb the -255 offset); tid>=192 fold bins
//   m/256-m into parity coefficient arrays, reading log_mag directly.
// Phase 2: gen on 129 threads. K symmetry (K[256-u]=K[256+u], K[0]=0) +
//   (n,n+256) pairing => one 65-step Chebyshev (E,O) gives 4 taps.
// Phase 3: conv, 16 k-groups x 16 threads, 16 outputs/thread, sliding
//   20-float register window: 12 ex + 8 ker b128 per 512 FMA.
// Phase 4: combine 16 partials, store.
__global__ __launch_bounds__(256)
void ltv_fir(const float* __restrict__ ex,
             const float* __restrict__ log_mag,
             float* __restrict__ out)
{
    __shared__ float s_d[2][132];        // [parity][m], [*][0]=[*][129..131]=0
    __shared__ float s_c[2];             // mag[0], mag[256]
    __shared__ float s_ker[512];
    __shared__ float s_ex[864];          // SWZ(767)=859
    __shared__ float s_part[16][260];

    const int tid = threadIdx.x;
    const int bf  = blockIdx.x;          // 0..1021
    const int b   = bf / NFRAMES;
    const int f   = bf - b * NFRAMES;

    const float* lm  = log_mag + ((size_t)b * 512 + f) * NBINS;
    const float* exb = ex + (size_t)b * TSAMP;

    // ---- phase 1: stage ex (tid<192) || fold coefficients (tid>=192) ----
    if (tid < 192) {
        const int gw = f * HOP - 256 + tid * 4;   // aligned global word base
        float4 q = make_float4(0.f, 0.f, 0.f, 0.f);
        if (gw >= 0) q = *(const float4*)&exb[gw];   // right edge always in range
        const int wb = tid * 4 - 1;                  // window idx of q.x
        if (tid > 0) s_ex[SWZ(wb)] = q.x;
        s_ex[SWZ(wb + 1)] = q.y;
        s_ex[SWZ(wb + 2)] = q.z;
        s_ex[SWZ(wb + 3)] = q.w;
    } else {
        #pragma unroll
        for (int it = 0; it < 3; ++it) {
            const int s2 = (tid - 192) + 64 * it;
            if (s2 < 134) {
                if (s2 == 132)      s_c[0] = __expf(lm[0]);
                else if (s2 == 133) s_c[1] = __expf(lm[256]);
                else if (s2 == 0 || s2 >= 129) { s_d[0][s2] = 0.f; s_d[1][s2] = 0.f; }
                else if (s2 == 128) { const float v = __expf(lm[128]); s_d[0][128] = v; s_d[1][128] = v; }
                else {
                    const float a  = __expf(lm[s2]);
                    const float c0 = __expf(lm[256 - s2]);
                    const float sg = (s2 & 1) ? -1.f : 1.f;
                    s_d[0][s2] = sg * (a + c0);   // even-parity taps
                    s_d[1][s2] = sg * (a - c0);   // odd-parity taps
                }
            }
        }
    }
    __syncthreads();

    // ---- phase 2: FIR kernel gen, 4 taps per (E,O) ----
    if (tid <= 128) {
        const int wid  = tid >> 6;
        const int lane = tid & 63;
        const int n    = (wid == 2) ? 128 : 2 * lane + wid;   // parity uniform/wave
        const float t  = __cosf(3.14159265358979323846f * (float)n * (1.0f / 256.0f));
        const float k2 = 2.0f * t;
        const float* dsel = s_d[n & 1];                       // wave-uniform ptr
        float ce = 1.0f, co = t, E = 0.0f, O = 0.0f;
        #pragma unroll 3
        for (int m = 0; m < 132; m += 4) {
            float4 dd = *(const float4*)&dsel[m];             // uniform b128 bcast
            E = fmaf(dd.x, ce, E);
            O = fmaf(dd.y, co, O);
            float ce2 = fmaf(k2, co,  -ce);
            float co2 = fmaf(k2, ce2, -co);
            E = fmaf(dd.z, ce2, E);
            O = fmaf(dd.w, co2, O);
            ce = fmaf(k2, co2, -ce2);
            co = fmaf(k2, ce,  -co2);
        }
        const float p    = (n & 1) ? -1.f : 1.f;
        const float cst  = s_c[0] + p * s_c[1];
        const float v_lo = (cst + 2.f * (E + O)) * (0.5f * (1.f - t)) * (1.f / 512.f);
        const float v_hi = (cst + 2.f * (E - O)) * (0.5f * (1.f + t)) * (1.f / 512.f);
        s_ker[n]       = v_lo;                    // K[n]
        s_ker[256 - n] = v_hi;                    // K[256-n] = K[256+n]
        if (n > 0) { s_ker[256 + n] = v_hi; s_ker[512 - n] = v_lo; }
    }
    __syncthreads();

    // ---- phase 3: conv partials; group g: taps [g*32, g*32+32),
    //      thread (g,lt): outputs j = lt*16 + r ----
    {
        const int g   = tid >> 4;
        const int lt  = tid & 15;
        const int kb  = g * 32;
        const int off = kb + lt * 16;             // ex window base for thread
        float w[20];
        #pragma unroll
        for (int c = 0; c < 5; ++c)
            *(float4*)&w[4 * c] = *(const float4*)&s_ex[SWZ(off + 4 * c)];
        float acc[16];
        #pragma unroll
        for (int r = 0; r < 16; ++r) acc[r] = 0.0f;
        #pragma unroll
        for (int kc = 0; kc < 32; kc += 4) {
            const float4 kq = *(const float4*)&s_ker[kb + kc];   // 4-addr bcast
            #pragma unroll
            for (int r = 0; r < 16; ++r)
                acc[r] = fmaf(w[r], kq.x, fmaf(w[r + 1], kq.y,
                         fmaf(w[r + 2], kq.z, fmaf(w[r + 3], kq.w, acc[r]))));
            if (kc < 28) {
                #pragma unroll
                for (int i = 0; i < 16; ++i) w[i] = w[i + 4];
                *(float4*)&w[16] = *(const float4*)&s_ex[SWZ(off + kc + 20)];
            }
        }
        #pragma unroll
        for (int c = 0; c < 4; ++c)
            *(float4*)&s_part[g][lt * 16 + 4 * c] =
                make_float4(acc[4 * c], acc[4 * c + 1], acc[4 * c + 2], acc[4 * c + 3]);
    }
    __syncthreads();

    // ---- phase 4: combine + store ----
    float r = 0.0f;
    #pragma unroll
    for (int gg = 0; gg < 16; ++gg) r += s_part[gg][tid];
    out[((size_t)b * NFRAMES + f) * HOP + tid] = r;
}

extern "C" void kernel_launch(void* const* d_in, const int* in_sizes, int n_in,
                              void* d_out, int out_size, void* d_ws, size_t ws_size,
                              hipStream_t stream)
{
    const float* ex      = (const float*)d_in[0];
    const float* log_mag = (const float*)d_in[1];
    float* out = (float*)d_out;

    dim3 grid(2 * NFRAMES);   // B * n_frames = 1022 blocks
    dim3 block(256);
    hipLaunchKernelGGL(ltv_fir, grid, block, 0, stream, ex, log_mag, out);
}